// Round 1
// baseline (435.418 us; speedup 1.0000x reference)
//
#include <hip/hip_runtime.h>
#include <math.h>

#define B_ 4
#define N_ 20000
#define S_ 2048
#define C_ 64
#define D_ 64
#define JSPLIT 8

__constant__ const float INV_T_unused = 0.f; // (not used; keep constants as literals)

typedef __bf16 bf16x8 __attribute__((ext_vector_type(8)));
typedef float f32x4 __attribute__((ext_vector_type(4)));

__device__ __forceinline__ unsigned short f2bf(float x) {
    unsigned int u = __float_as_uint(x);
    unsigned int r = (u + 0x7fffu + ((u >> 16) & 1u)) >> 16;
    return (unsigned short)r;
}

// ---------------------------------------------------------------------------
// Kernel 1: inverse permutation.  inv[b][shuf[b][i]] = i
// ---------------------------------------------------------------------------
__global__ void k_invperm(const int* __restrict__ shuf, int* __restrict__ inv) {
    int t = blockIdx.x * blockDim.x + threadIdx.x;
    if (t < B_ * N_) {
        int b = t / N_;
        int i = t - b * N_;
        inv[b * N_ + shuf[t]] = i;
    }
}

// ---------------------------------------------------------------------------
// Kernel 2: gather + L2-normalize both feature rows, store bf16, fp32 diag.
// One wave per (b,s) sample. lane = channel (C=64 = wave width).
// ---------------------------------------------------------------------------
__global__ __launch_bounds__(256) void k_gather(
    const float* __restrict__ dv, const int* __restrict__ vcoor,
    const float* __restrict__ df, const int* __restrict__ fcoor,
    const int* __restrict__ inv, const int* __restrict__ samp,
    unsigned short* __restrict__ vf, unsigned short* __restrict__ ff,
    float* __restrict__ diag, float* __restrict__ rowsum) {
    int wave = threadIdx.x >> 6;
    int lane = threadIdx.x & 63;
    int idx = blockIdx.x * 4 + wave;      // = b*S + s,  in [0, B*S)
    int b = idx >> 11;                    // S = 2048

    int sm = samp[idx];

    // vehicle side
    const int* vc = vcoor + (b * N_ + sm) * 3;
    int a0 = vc[0] >> 3, a1 = vc[1] >> 3, a2 = vc[2] >> 3;
    float vval = dv[((((long)b * D_ + a0) * D_ + a1) * D_ + a2) * C_ + lane];
    float ss = vval * vval;
    #pragma unroll
    for (int m = 32; m; m >>= 1) ss += __shfl_xor(ss, m, 64);
    float vn = vval * (1.0f / fmaxf(sqrtf(ss), 1e-12f));

    // fusion side (through inverse permutation)
    int f_id = inv[b * N_ + sm];
    const int* fc = fcoor + (b * N_ + f_id) * 3;
    int c0 = fc[0] >> 3, c1 = fc[1] >> 3, c2 = fc[2] >> 3;
    float fval = df[((((long)b * D_ + c0) * D_ + c1) * D_ + c2) * C_ + lane];
    float fs = fval * fval;
    #pragma unroll
    for (int m = 32; m; m >>= 1) fs += __shfl_xor(fs, m, 64);
    float fn = fval * (1.0f / fmaxf(sqrtf(fs), 1e-12f));

    // diagonal dot product in fp32
    float dd = vn * fn;
    #pragma unroll
    for (int m = 32; m; m >>= 1) dd += __shfl_xor(dd, m, 64);

    vf[idx * C_ + lane] = f2bf(vn);
    ff[idx * C_ + lane] = f2bf(fn);
    if (lane == 0) {
        diag[idx] = dd;
        rowsum[idx] = 0.0f;
    }
}

// ---------------------------------------------------------------------------
// Kernel 3: bf16 MFMA scores + exp + row-sum.
// Wave owns a 16-row strip (A frags in registers), sweeps 1/JSPLIT of j.
// 16x16x32 bf16 MFMA; A and B fragments are both "row = lane&15, 8 contig k
// at (lane>>4)*8" -> plain 16B loads from the packed bf16 feature arrays.
// C/D layout: col = lane&15, row = (lane>>4)*4 + reg.
// ---------------------------------------------------------------------------
__global__ __launch_bounds__(256) void k_scores(
    const unsigned short* __restrict__ vf, const unsigned short* __restrict__ ff,
    float* __restrict__ rowsum) {
    const float invT = 1.0f / 0.7f;
    int bx = blockIdx.x;                 // B * (S/64) * JSPLIT blocks
    int js = bx & (JSPLIT - 1);
    int t  = bx / JSPLIT;
    int rb = t & 31;                     // 32 row-blocks of 64
    int b  = t >> 5;

    int wave = threadIdx.x >> 6;
    int lane = threadIdx.x & 63;
    int m = lane & 15;                   // fragment row
    int q = lane >> 4;                   // k-quad: k offset q*8

    int row16 = rb * 64 + wave * 16;     // this wave's row-strip base

    const unsigned short* arow = vf + ((size_t)(b * S_ + row16 + m)) * C_ + q * 8;
    bf16x8 afr0 = *reinterpret_cast<const bf16x8*>(arow);
    bf16x8 afr1 = *reinterpret_cast<const bf16x8*>(arow + 32);

    int j0 = js * (S_ / JSPLIT);
    const unsigned short* fbase = ff + ((size_t)(b * S_ + j0 + m)) * C_ + q * 8;

    float r0 = 0.f, r1 = 0.f, r2 = 0.f, r3 = 0.f;

    #pragma unroll 4
    for (int jt = 0; jt < (S_ / JSPLIT) / 16; ++jt) {
        const unsigned short* brow = fbase + (size_t)jt * 16 * C_;
        bf16x8 bfr0 = *reinterpret_cast<const bf16x8*>(brow);
        bf16x8 bfr1 = *reinterpret_cast<const bf16x8*>(brow + 32);
        f32x4 c = {0.f, 0.f, 0.f, 0.f};
        c = __builtin_amdgcn_mfma_f32_16x16x32_bf16(afr0, bfr0, c, 0, 0, 0);
        c = __builtin_amdgcn_mfma_f32_16x16x32_bf16(afr1, bfr1, c, 0, 0, 0);
        r0 += __expf(c[0] * invT);
        r1 += __expf(c[1] * invT);
        r2 += __expf(c[2] * invT);
        r3 += __expf(c[3] * invT);
    }

    // reduce across the 16 columns (lane bits 0..3)
    #pragma unroll
    for (int msk = 1; msk < 16; msk <<= 1) {
        r0 += __shfl_xor(r0, msk, 64);
        r1 += __shfl_xor(r1, msk, 64);
        r2 += __shfl_xor(r2, msk, 64);
        r3 += __shfl_xor(r3, msk, 64);
    }

    if (m == 0) {
        float* rs = rowsum + b * S_ + row16 + q * 4;
        atomicAdd(rs + 0, r0);
        atomicAdd(rs + 1, r1);
        atomicAdd(rs + 2, r2);
        atomicAdd(rs + 3, r3);
    }
}

// ---------------------------------------------------------------------------
// Kernel 4: final loss = sum_{b,i} (log(rowsum) - diag/T) / S
// ---------------------------------------------------------------------------
__global__ __launch_bounds__(256) void k_loss(
    const float* __restrict__ rowsum, const float* __restrict__ diag,
    float* __restrict__ out) {
    const float invT = 1.0f / 0.7f;
    __shared__ float red[256];
    float acc = 0.f;
    for (int i = threadIdx.x; i < B_ * S_; i += 256) {
        acc += logf(rowsum[i]) - diag[i] * invT;
    }
    red[threadIdx.x] = acc;
    __syncthreads();
    for (int s = 128; s; s >>= 1) {
        if (threadIdx.x < s) red[threadIdx.x] += red[threadIdx.x + s];
        __syncthreads();
    }
    if (threadIdx.x == 0) out[0] = red[0] / (float)S_;
}

// ---------------------------------------------------------------------------
extern "C" void kernel_launch(void* const* d_in, const int* in_sizes, int n_in,
                              void* d_out, int out_size, void* d_ws, size_t ws_size,
                              hipStream_t stream) {
    const float* dense_v = (const float*)d_in[0];
    const int*   vcoor   = (const int*)d_in[1];
    const float* dense_f = (const float*)d_in[2];
    const int*   fcoor   = (const int*)d_in[3];
    const int*   shuf    = (const int*)d_in[4];
    // d_in[5] = vehicle_points (unused by the reference loss)
    const int*   samp    = (const int*)d_in[6];
    float* out = (float*)d_out;

    char* ws = (char*)d_ws;
    int*            inv    = (int*)(ws + 0);                       // B*N int   = 320000 B
    unsigned short* vf     = (unsigned short*)(ws + 320000);       // B*S*64 bf16 = 1048576 B
    unsigned short* ff     = (unsigned short*)(ws + 1368576);      // B*S*64 bf16 = 1048576 B
    float*          diag   = (float*)(ws + 2417152);               // B*S f32 = 32768 B
    float*          rowsum = (float*)(ws + 2449920);               // B*S f32 = 32768 B

    k_invperm<<<(B_ * N_ + 255) / 256, 256, 0, stream>>>(shuf, inv);
    k_gather<<<(B_ * S_) / 4, 256, 0, stream>>>(dense_v, vcoor, dense_f, fcoor,
                                                inv, samp, vf, ff, diag, rowsum);
    k_scores<<<B_ * (S_ / 64) * JSPLIT, 256, 0, stream>>>(vf, ff, rowsum);
    k_loss<<<1, 256, 0, stream>>>(rowsum, diag, out);
}

// Round 2
// 431.932 us; speedup vs baseline: 1.0081x; 1.0081x over previous
//
#include <hip/hip_runtime.h>
#include <math.h>

#define B_ 4
#define N_ 20000
#define S_ 2048
#define C_ 64
#define D_ 64
#define JSPLIT 8

typedef __bf16 bf16x8 __attribute__((ext_vector_type(8)));
typedef float f32x4 __attribute__((ext_vector_type(4)));

// exp(c / T) = exp2(c * (log2(e)/T)); T = 0.7
#define EXP_SCALE 2.0609929156f

__device__ __forceinline__ unsigned short f2bf(float x) {
    unsigned int u = __float_as_uint(x);
    unsigned int r = (u + 0x7fffu + ((u >> 16) & 1u)) >> 16;
    return (unsigned short)r;
}

// ---------------------------------------------------------------------------
// Kernel 1: inverse permutation.  inv[b][shuf[b][i]] = i
// ---------------------------------------------------------------------------
__global__ void k_invperm(const int* __restrict__ shuf, int* __restrict__ inv) {
    int t = blockIdx.x * blockDim.x + threadIdx.x;
    if (t < B_ * N_) {
        int b = t / N_;
        int i = t - b * N_;
        inv[b * N_ + shuf[t]] = i;
    }
}

// ---------------------------------------------------------------------------
// Kernel 2: gather + L2-normalize both feature rows, store bf16, fp32 diag.
// One wave per (b,s) sample. lane = channel (C=64 = wave width).
// ---------------------------------------------------------------------------
__global__ __launch_bounds__(256) void k_gather(
    const float* __restrict__ dv, const int* __restrict__ vcoor,
    const float* __restrict__ df, const int* __restrict__ fcoor,
    const int* __restrict__ inv, const int* __restrict__ samp,
    unsigned short* __restrict__ vf, unsigned short* __restrict__ ff,
    float* __restrict__ diag, float* __restrict__ rowsum) {
    int wave = threadIdx.x >> 6;
    int lane = threadIdx.x & 63;
    int idx = blockIdx.x * 4 + wave;      // = b*S + s,  in [0, B*S)
    int b = idx >> 11;                    // S = 2048

    int sm = samp[idx];

    // issue the two independent index loads up front (shorten dep chain)
    const int* vc = vcoor + (b * N_ + sm) * 3;
    int f_id = inv[b * N_ + sm];

    int a0 = vc[0] >> 3, a1 = vc[1] >> 3, a2 = vc[2] >> 3;
    float vval = dv[((((long)b * D_ + a0) * D_ + a1) * D_ + a2) * C_ + lane];

    const int* fc = fcoor + (b * N_ + f_id) * 3;
    int c0 = fc[0] >> 3, c1 = fc[1] >> 3, c2 = fc[2] >> 3;
    float fval = df[((((long)b * D_ + c0) * D_ + c1) * D_ + c2) * C_ + lane];

    float ss = vval * vval;
    #pragma unroll
    for (int m = 32; m; m >>= 1) ss += __shfl_xor(ss, m, 64);
    float vn = vval * (1.0f / fmaxf(sqrtf(ss), 1e-12f));

    float fs = fval * fval;
    #pragma unroll
    for (int m = 32; m; m >>= 1) fs += __shfl_xor(fs, m, 64);
    float fn = fval * (1.0f / fmaxf(sqrtf(fs), 1e-12f));

    // diagonal dot product in fp32
    float dd = vn * fn;
    #pragma unroll
    for (int m = 32; m; m >>= 1) dd += __shfl_xor(dd, m, 64);

    vf[idx * C_ + lane] = f2bf(vn);
    ff[idx * C_ + lane] = f2bf(fn);
    if (lane == 0) {
        diag[idx] = dd;
        rowsum[idx] = 0.0f;
    }
}

// ---------------------------------------------------------------------------
// Kernel 3: bf16 MFMA scores + exp + row-sum.
// Wave owns a 16-row strip (A frags in registers), sweeps 1/JSPLIT of j,
// two 16-col j-tiles per iteration for load ILP.
// A/B frag: row = lane&15, 8 contig k at (lane>>4)*8  -> plain 16B loads.
// C/D: col = lane&15, row = (lane>>4)*4 + reg.
// ---------------------------------------------------------------------------
__global__ __launch_bounds__(256) void k_scores(
    const unsigned short* __restrict__ vf, const unsigned short* __restrict__ ff,
    float* __restrict__ rowsum) {
    int bx = blockIdx.x;                 // B * (S/64) * JSPLIT blocks
    int js = bx & (JSPLIT - 1);
    int t  = bx / JSPLIT;
    int rb = t & 31;                     // 32 row-blocks of 64
    int b  = t >> 5;

    int wave = threadIdx.x >> 6;
    int lane = threadIdx.x & 63;
    int m = lane & 15;                   // fragment row
    int q = lane >> 4;                   // k-quad: k offset q*8

    int row16 = rb * 64 + wave * 16;     // this wave's row-strip base

    const unsigned short* arow = vf + ((size_t)(b * S_ + row16 + m)) * C_ + q * 8;
    bf16x8 afr0 = *reinterpret_cast<const bf16x8*>(arow);
    bf16x8 afr1 = *reinterpret_cast<const bf16x8*>(arow + 32);

    int j0 = js * (S_ / JSPLIT);
    const unsigned short* fbase = ff + ((size_t)(b * S_ + j0 + m)) * C_ + q * 8;

    float r0 = 0.f, r1 = 0.f, r2 = 0.f, r3 = 0.f;

    #pragma unroll 4
    for (int jt = 0; jt < (S_ / JSPLIT) / 16; jt += 2) {
        const unsigned short* brow0 = fbase + (size_t)jt * 16 * C_;
        const unsigned short* brow1 = brow0 + 16 * C_;
        bf16x8 b00 = *reinterpret_cast<const bf16x8*>(brow0);
        bf16x8 b01 = *reinterpret_cast<const bf16x8*>(brow0 + 32);
        bf16x8 b10 = *reinterpret_cast<const bf16x8*>(brow1);
        bf16x8 b11 = *reinterpret_cast<const bf16x8*>(brow1 + 32);
        f32x4 c0 = {0.f, 0.f, 0.f, 0.f};
        f32x4 c1 = {0.f, 0.f, 0.f, 0.f};
        c0 = __builtin_amdgcn_mfma_f32_16x16x32_bf16(afr0, b00, c0, 0, 0, 0);
        c1 = __builtin_amdgcn_mfma_f32_16x16x32_bf16(afr0, b10, c1, 0, 0, 0);
        c0 = __builtin_amdgcn_mfma_f32_16x16x32_bf16(afr1, b01, c0, 0, 0, 0);
        c1 = __builtin_amdgcn_mfma_f32_16x16x32_bf16(afr1, b11, c1, 0, 0, 0);
        r0 += __builtin_amdgcn_exp2f(c0[0] * EXP_SCALE);
        r1 += __builtin_amdgcn_exp2f(c0[1] * EXP_SCALE);
        r2 += __builtin_amdgcn_exp2f(c0[2] * EXP_SCALE);
        r3 += __builtin_amdgcn_exp2f(c0[3] * EXP_SCALE);
        r0 += __builtin_amdgcn_exp2f(c1[0] * EXP_SCALE);
        r1 += __builtin_amdgcn_exp2f(c1[1] * EXP_SCALE);
        r2 += __builtin_amdgcn_exp2f(c1[2] * EXP_SCALE);
        r3 += __builtin_amdgcn_exp2f(c1[3] * EXP_SCALE);
    }

    // reduce across the 16 columns (lane bits 0..3)
    #pragma unroll
    for (int msk = 1; msk < 16; msk <<= 1) {
        r0 += __shfl_xor(r0, msk, 64);
        r1 += __shfl_xor(r1, msk, 64);
        r2 += __shfl_xor(r2, msk, 64);
        r3 += __shfl_xor(r3, msk, 64);
    }

    if (m == 0) {
        float* rs = rowsum + b * S_ + row16 + q * 4;
        atomicAdd(rs + 0, r0);
        atomicAdd(rs + 1, r1);
        atomicAdd(rs + 2, r2);
        atomicAdd(rs + 3, r3);
    }
}

// ---------------------------------------------------------------------------
// Kernel 4: final loss = sum_{b,i} (log(rowsum) - diag/T) / S
// ---------------------------------------------------------------------------
__global__ __launch_bounds__(256) void k_loss(
    const float* __restrict__ rowsum, const float* __restrict__ diag,
    float* __restrict__ out) {
    const float invT = 1.0f / 0.7f;
    __shared__ float red[256];
    float acc = 0.f;
    for (int i = threadIdx.x; i < B_ * S_; i += 256) {
        acc += logf(rowsum[i]) - diag[i] * invT;
    }
    red[threadIdx.x] = acc;
    __syncthreads();
    for (int s = 128; s; s >>= 1) {
        if (threadIdx.x < s) red[threadIdx.x] += red[threadIdx.x + s];
        __syncthreads();
    }
    if (threadIdx.x == 0) out[0] = red[0] / (float)S_;
}

// ---------------------------------------------------------------------------
extern "C" void kernel_launch(void* const* d_in, const int* in_sizes, int n_in,
                              void* d_out, int out_size, void* d_ws, size_t ws_size,
                              hipStream_t stream) {
    const float* dense_v = (const float*)d_in[0];
    const int*   vcoor   = (const int*)d_in[1];
    const float* dense_f = (const float*)d_in[2];
    const int*   fcoor   = (const int*)d_in[3];
    const int*   shuf    = (const int*)d_in[4];
    // d_in[5] = vehicle_points (unused by the reference loss)
    const int*   samp    = (const int*)d_in[6];
    float* out = (float*)d_out;

    char* ws = (char*)d_ws;
    int*            inv    = (int*)(ws + 0);                       // B*N int   = 320000 B
    unsigned short* vf     = (unsigned short*)(ws + 320000);       // B*S*64 bf16 = 1048576 B
    unsigned short* ff     = (unsigned short*)(ws + 1368576);      // B*S*64 bf16 = 1048576 B
    float*          diag   = (float*)(ws + 2417152);               // B*S f32 = 32768 B
    float*          rowsum = (float*)(ws + 2449920);               // B*S f32 = 32768 B

    k_invperm<<<(B_ * N_ + 255) / 256, 256, 0, stream>>>(shuf, inv);
    k_gather<<<(B_ * S_) / 4, 256, 0, stream>>>(dense_v, vcoor, dense_f, fcoor,
                                                inv, samp, vf, ff, diag, rowsum);
    k_scores<<<B_ * (S_ / 64) * JSPLIT, 256, 0, stream>>>(vf, ff, rowsum);
    k_loss<<<1, 256, 0, stream>>>(rowsum, diag, out);
}